// Round 1
// baseline (133.899 us; speedup 1.0000x reference)
//
#include <hip/hip_runtime.h>

// MonarchLinear: x[16384,256] fp32, L[68,68,68], R[68,68,68], bias[4608] -> out[16384,4608] fp32.
// Only blocks k=0..3 of the padded (4624) input are nonzero:
//   t1[b,r,l] = sum_p x[b, r*68+p] * L[r,l,p]           (r<4; r==3 only p<52 valid)
//   out[b, s*68+l] = sum_{r<4} t1[b,r,l] * R[l,s,r] + bias[s*68+l]
// Memory-bound: 302 MB output write dominates (~50 us floor at 6.3 TB/s).

typedef float f4 __attribute__((ext_vector_type(4)));

namespace {
constexpr int MM     = 68;        // Monarch block size
constexpr int IN_D   = 256;
constexpr int OUT_D  = 4608;
constexpr int T_TILE = 16;        // tokens per block
constexpr int NTH    = 256;       // threads per block (4 waves)
constexpr int NV     = OUT_D / 4; // 1152 float4 output chunks per token
constexpr int NCHUNK = (NV + NTH - 1) / NTH; // 5 chunks per thread (last half-populated)
}

__global__ __launch_bounds__(NTH, 2)
void monarch_fused(const float* __restrict__ x, const float* __restrict__ L,
                   const float* __restrict__ R, const float* __restrict__ bias,
                   float* __restrict__ out)
{
  __shared__ float t1s[T_TILE * 4 * MM];   // [t][r*68 + l], 17408 B
  const int tid = threadIdx.x;
  const long tb = (long)blockIdx.x * T_TILE;

  // ---- hoist R coefficients + bias for this thread's output chunks into regs ----
  // chunk v covers out columns j = 4v..4v+3; s = v/17, l = 4*(v%17)+q (no l-wrap
  // inside a float4 since 68 = 4*17). Rr[i][q] = R[l][s][0..3] (16B aligned).
  f4 Rr[NCHUNK][4];
  f4 br[NCHUNK];
  int l4a[NCHUNK];
#pragma unroll
  for (int i = 0; i < NCHUNK; ++i) {
    int v = tid + i * NTH;
    if (v < NV) {                       // wave-uniform predicate (tid<128 at i==4)
      int s  = v / 17;
      int l4 = (v - s * 17) * 4;
      l4a[i] = l4;
      br[i]  = *(const f4*)(bias + 4 * v);
#pragma unroll
      for (int q = 0; q < 4; ++q)
        Rr[i][q] = *(const f4*)(R + (size_t)(l4 + q) * (MM * MM) + (size_t)s * MM);
    }
  }

  // ---- stage 1: t1[r*68+l] for 16 tokens, x/L read direct from global (L1-hot) ----
  for (int idx = tid; idx < 4 * MM; idx += NTH) {   // 272 tasks; 2nd round: tid<16
    const int r = idx / MM;             // 0..3
    const float* Lp = L + (size_t)idx * MM;             // L[r][l][*] contiguous
    const float* xp = x + tb * IN_D + r * MM;
    // r==3: columns 204+p valid only for p<52 (rest is zero padding) -> clamp
    const int p4max = (r == 3) ? (IN_D - 3 * MM) / 4 : MM / 4;   // 13 or 17
    float acc[T_TILE];
#pragma unroll
    for (int t = 0; t < T_TILE; ++t) acc[t] = 0.f;
    for (int p4 = 0; p4 < p4max; ++p4) {
      f4 Lv = *(const f4*)(Lp + p4 * 4);
#pragma unroll
      for (int t = 0; t < T_TILE; ++t) {
        f4 xv = *(const f4*)(xp + (size_t)t * IN_D + p4 * 4);  // broadcast within r-group
        acc[t] = fmaf(Lv.x, xv.x, acc[t]);
        acc[t] = fmaf(Lv.y, xv.y, acc[t]);
        acc[t] = fmaf(Lv.z, xv.z, acc[t]);
        acc[t] = fmaf(Lv.w, xv.w, acc[t]);
      }
    }
#pragma unroll
    for (int t = 0; t < T_TILE; ++t) t1s[t * (4 * MM) + idx] = acc[t];
  }
  __syncthreads();

  // ---- stage 2: out[j] = sum_r t1[r][l]*R[l][s][r] + bias[j], float4 NT stores ----
#pragma unroll 1
  for (int t = 0; t < T_TILE; ++t) {
    const float* t1p = t1s + t * (4 * MM);
    float* op = out + (tb + t) * OUT_D;
#pragma unroll
    for (int i = 0; i < NCHUNK; ++i) {
      int v = tid + i * NTH;
      if (v < NV) {
        const int l4 = l4a[i];
        f4 a0 = *(const f4*)(t1p + l4);            // conflict-free-ish b128 (16B lane stride)
        f4 a1 = *(const f4*)(t1p + MM + l4);
        f4 a2 = *(const f4*)(t1p + 2 * MM + l4);
        f4 a3 = *(const f4*)(t1p + 3 * MM + l4);
        f4 o;
#pragma unroll
        for (int q = 0; q < 4; ++q) {
          float oq = br[i][q];
          oq = fmaf(a0[q], Rr[i][q].x, oq);
          oq = fmaf(a1[q], Rr[i][q].y, oq);
          oq = fmaf(a2[q], Rr[i][q].z, oq);
          oq = fmaf(a3[q], Rr[i][q].w, oq);
          o[q] = oq;
        }
        __builtin_nontemporal_store(o, (f4*)(op + 4 * v));
      }
    }
  }
}

extern "C" void kernel_launch(void* const* d_in, const int* in_sizes, int n_in,
                              void* d_out, int out_size, void* d_ws, size_t ws_size,
                              hipStream_t stream) {
  const float* x    = (const float*)d_in[0];
  const float* L    = (const float*)d_in[1];
  const float* R    = (const float*)d_in[2];
  const float* bias = (const float*)d_in[3];
  float* out = (float*)d_out;

  const int ntok = in_sizes[0] / IN_D;       // 16384
  dim3 grid(ntok / T_TILE);                  // 1024 blocks x 256 threads
  monarch_fused<<<grid, NTH, 0, stream>>>(x, L, R, bias, out);
}